// Round 1
// baseline (949.329 us; speedup 1.0000x reference)
//
#include <hip/hip_runtime.h>
#include <hip/hip_bf16.h>

#define WSZ 16
#define OWSZ 24
#define NH 6
#define DIM 192
#define HW 192
#define NWIN 12
#define M_TOK (HW*HW)

typedef __attribute__((ext_vector_type(8))) __bf16 bf16x8;
typedef __attribute__((ext_vector_type(8))) short short8;
typedef __attribute__((ext_vector_type(4))) float floatx4;

__device__ inline unsigned short f2bf(float f) {
    union { float f; unsigned int u; } v; v.f = f;
    unsigned int r = (v.u + 0x7FFFu + ((v.u >> 16) & 1u)) >> 16;
    return (unsigned short)r;
}
__device__ inline float bf2f(unsigned short h) {
    union { unsigned int u; float f; } v; v.u = ((unsigned int)h) << 16;
    return v.f;
}

__device__ inline floatx4 mfma16(short8 a, short8 b, floatx4 c) {
    return __builtin_amdgcn_mfma_f32_16x16x32_bf16(
        __builtin_bit_cast(bf16x8, a), __builtin_bit_cast(bf16x8, b), c, 0, 0, 0);
}

// ---- cast + transpose weight: w (K x N) f32 -> wt (N x K) bf16 ----
__global__ void wcast_kernel(const float* __restrict__ w, unsigned short* __restrict__ wt,
                             int K, int N) {
    int id = blockIdx.x * 256 + threadIdx.x;
    if (id >= K * N) return;
    int n = id / K, k = id - n * K;
    wt[id] = f2bf(w[k * N + n]);
}

// ---- expand relative position bias: bt[h][k][q] ----
__global__ void biast_kernel(const int* __restrict__ rpi, const float* __restrict__ table,
                             float* __restrict__ bt) {
    int id = blockIdx.x * 256 + threadIdx.x;
    if (id >= NH * 576 * 256) return;
    int q = id & 255;
    int hk = id >> 8;
    int k = hk % 576;
    int h = hk / 576;
    bt[id] = table[rpi[q * 576 + k] * NH + h];
}

// ---- LayerNorm: f32 in -> bf16 out, one wave per row of 192 ----
__global__ __launch_bounds__(256) void ln_kernel(const float* __restrict__ in,
                                                 const float* __restrict__ g,
                                                 const float* __restrict__ b,
                                                 unsigned short* __restrict__ out) {
    int row = blockIdx.x * 4 + (threadIdx.x >> 6);
    int lane = threadIdx.x & 63;
    const float* r = in + (size_t)row * DIM;
    float x0 = r[lane], x1 = r[lane + 64], x2 = r[lane + 128];
    float s = x0 + x1 + x2;
    #pragma unroll
    for (int m = 32; m >= 1; m >>= 1) s += __shfl_xor(s, m);
    float mean = s * (1.f / 192.f);
    float d0 = x0 - mean, d1 = x1 - mean, d2 = x2 - mean;
    float v = d0 * d0 + d1 * d1 + d2 * d2;
    #pragma unroll
    for (int m = 32; m >= 1; m >>= 1) v += __shfl_xor(v, m);
    float rstd = rsqrtf(v * (1.f / 192.f) + 1e-5f);
    unsigned short* o = out + (size_t)row * DIM;
    o[lane]       = f2bf(d0 * rstd * g[lane]       + b[lane]);
    o[lane + 64]  = f2bf(d1 * rstd * g[lane + 64]  + b[lane + 64]);
    o[lane + 128] = f2bf(d2 * rstd * g[lane + 128] + b[lane + 128]);
}

// ---- generic bf16 MFMA GEMM: A (M x K) @ Wt^T (Wt is N x K) + bias ----
// MODE 0: out bf16 = acc + bias
// MODE 1: out f32  = acc + bias + res           (proj + shortcut)
// MODE 2: out bf16 = gelu(acc + bias)           (fc1)
// MODE 3: out f32  = acc + bias + out (in-place) (fc2 + x2)
template <int MODE>
__global__ __launch_bounds__(256, 2) void gemm_kernel(
    const unsigned short* __restrict__ A,
    const unsigned short* __restrict__ Wt,
    const float* __restrict__ bias,
    const float* __restrict__ res,
    void* __restrict__ outp,
    int M, int N, int K) {
    __shared__ short sA[128 * 72];
    __shared__ short sB[64 * 72];
    int tid = threadIdx.x;
    int bn = blockIdx.x, bm = blockIdx.y;
    int w = tid >> 6, lane = tid & 63;
    int lr = lane & 15, lk = (lane >> 4) * 8;
    floatx4 acc[2][4];
    #pragma unroll
    for (int i = 0; i < 2; i++)
        #pragma unroll
        for (int j = 0; j < 4; j++) acc[i][j] = (floatx4){0.f, 0.f, 0.f, 0.f};

    int tr = tid >> 3, tc = (tid & 7) * 8;
    const size_t abase = (size_t)(bm * 128) * K;
    const size_t bbase = (size_t)(bn * 64) * K;

    for (int k0 = 0; k0 < K; k0 += 64) {
        if (k0) __syncthreads();
        #pragma unroll
        for (int p = 0; p < 4; p++) {
            int row = p * 32 + tr;
            *(short8*)&sA[row * 72 + tc] =
                *(const short8*)&A[abase + (size_t)row * K + k0 + tc];
        }
        #pragma unroll
        for (int p = 0; p < 2; p++) {
            int row = p * 32 + tr;
            *(short8*)&sB[row * 72 + tc] =
                *(const short8*)&Wt[bbase + (size_t)row * K + k0 + tc];
        }
        __syncthreads();
        #pragma unroll
        for (int kk = 0; kk < 2; kk++) {
            short8 a0 = *(short8*)&sA[(w * 32 + lr) * 72 + kk * 32 + lk];
            short8 a1 = *(short8*)&sA[(w * 32 + 16 + lr) * 72 + kk * 32 + lk];
            short8 b0 = *(short8*)&sB[(lr) * 72 + kk * 32 + lk];
            short8 b1 = *(short8*)&sB[(16 + lr) * 72 + kk * 32 + lk];
            short8 b2 = *(short8*)&sB[(32 + lr) * 72 + kk * 32 + lk];
            short8 b3 = *(short8*)&sB[(48 + lr) * 72 + kk * 32 + lk];
            acc[0][0] = mfma16(a0, b0, acc[0][0]);
            acc[0][1] = mfma16(a0, b1, acc[0][1]);
            acc[0][2] = mfma16(a0, b2, acc[0][2]);
            acc[0][3] = mfma16(a0, b3, acc[0][3]);
            acc[1][0] = mfma16(a1, b0, acc[1][0]);
            acc[1][1] = mfma16(a1, b1, acc[1][1]);
            acc[1][2] = mfma16(a1, b2, acc[1][2]);
            acc[1][3] = mfma16(a1, b3, acc[1][3]);
        }
    }

    int rowbase = bm * 128 + w * 32 + (lane >> 4) * 4;
    int colbase = bn * 64;
    #pragma unroll
    for (int mi = 0; mi < 2; mi++) {
        #pragma unroll
        for (int ni = 0; ni < 4; ni++) {
            int c = colbase + ni * 16 + lr;
            float bv = bias[c];
            #pragma unroll
            for (int j = 0; j < 4; j++) {
                int r = rowbase + mi * 16 + j;
                size_t idx = (size_t)r * N + c;
                float v = acc[mi][ni][j] + bv;
                if (MODE == 0) {
                    ((unsigned short*)outp)[idx] = f2bf(v);
                } else if (MODE == 1) {
                    ((float*)outp)[idx] = v + res[idx];
                } else if (MODE == 2) {
                    float gl = 0.5f * v * (1.f + erff(v * 0.70710678118654752f));
                    ((unsigned short*)outp)[idx] = f2bf(gl);
                } else {
                    ((float*)outp)[idx] = v + ((float*)outp)[idx];
                }
            }
        }
    }
}

// ---- windowed attention, one block per (window, head), 1 thread = 1 query ----
__global__ __launch_bounds__(256, 2) void attn_kernel(
    const unsigned short* __restrict__ qkv,
    const float* __restrict__ bt,
    unsigned short* __restrict__ out) {
    __shared__ float sk[192 * 36];
    __shared__ float sv[192 * 36];
    int win = blockIdx.x, head = blockIdx.y;
    int iy = win / NWIN, ix = win % NWIN;
    int tid = threadIdx.x;
    int qy = tid >> 4, qx = tid & 15;
    size_t ti = (size_t)(iy * 16 + qy) * HW + ix * 16 + qx;

    float qf[32];
    {
        const short8* qp = (const short8*)&qkv[ti * 576 + head * 32];
        #pragma unroll
        for (int c = 0; c < 4; c++) {
            short8 v = qp[c];
            #pragma unroll
            for (int j = 0; j < 8; j++)
                qf[c * 8 + j] = bf2f((unsigned short)v[j]) * 0.17677669529663689f;
        }
    }

    float l = 0.f;
    float o[32];
    #pragma unroll
    for (int d = 0; d < 32; d++) o[d] = 0.f;

    const float* btq = bt + (size_t)head * 576 * 256 + tid;

    for (int chunk = 0; chunk < 3; chunk++) {
        __syncthreads();
        if (tid < 192) {
            int t = chunk * 192 + tid;
            int oy = t / 24, ox = t - (t / 24) * 24;
            int gy = iy * 16 - 4 + oy, gx = ix * 16 - 4 + ox;
            float kf[32], vf[32];
            if (gy >= 0 && gy < HW && gx >= 0 && gx < HW) {
                size_t base = ((size_t)gy * HW + gx) * 576 + 192 + head * 32;
                const short8* kp = (const short8*)&qkv[base];
                const short8* vp = (const short8*)&qkv[base + 192];
                #pragma unroll
                for (int c = 0; c < 4; c++) {
                    short8 a = kp[c], b = vp[c];
                    #pragma unroll
                    for (int j = 0; j < 8; j++) {
                        kf[c * 8 + j] = bf2f((unsigned short)a[j]);
                        vf[c * 8 + j] = bf2f((unsigned short)b[j]);
                    }
                }
            } else {
                #pragma unroll
                for (int d = 0; d < 32; d++) { kf[d] = 0.f; vf[d] = 0.f; }
            }
            #pragma unroll
            for (int c = 0; c < 8; c++) {
                floatx4 kv4 = {kf[c * 4], kf[c * 4 + 1], kf[c * 4 + 2], kf[c * 4 + 3]};
                floatx4 vv4 = {vf[c * 4], vf[c * 4 + 1], vf[c * 4 + 2], vf[c * 4 + 3]};
                *(floatx4*)&sk[tid * 36 + c * 4] = kv4;
                *(floatx4*)&sv[tid * 36 + c * 4] = vv4;
            }
        }
        __syncthreads();

        const float* bp = btq + (size_t)chunk * 192 * 256;
        #pragma unroll 4
        for (int kk = 0; kk < 192; kk++) {
            const float* kr = &sk[kk * 36];
            float s0 = 0.f, s1 = 0.f, s2 = 0.f, s3 = 0.f;
            #pragma unroll
            for (int d = 0; d < 32; d += 4) {
                s0 += qf[d] * kr[d];
                s1 += qf[d + 1] * kr[d + 1];
                s2 += qf[d + 2] * kr[d + 2];
                s3 += qf[d + 3] * kr[d + 3];
            }
            float s = (s0 + s1) + (s2 + s3) + bp[kk * 256];
            float p = __expf(s);
            l += p;
            const float* vr = &sv[kk * 36];
            #pragma unroll
            for (int d = 0; d < 32; d++) o[d] += p * vr[d];
        }
    }

    float inv = 1.f / l;
    unsigned short* op = out + ti * DIM + head * 32;
    #pragma unroll
    for (int c = 0; c < 4; c++) {
        short8 v;
        #pragma unroll
        for (int j = 0; j < 8; j++) v[j] = (short)f2bf(o[c * 8 + j] * inv);
        *(short8*)&op[c * 8] = v;
    }
}

extern "C" void kernel_launch(void* const* d_in, const int* in_sizes, int n_in,
                              void* d_out, int out_size, void* d_ws, size_t ws_size,
                              hipStream_t stream) {
    const float* x     = (const float*)d_in[0];
    const int*   rpi   = (const int*)d_in[1];
    const float* n1g   = (const float*)d_in[4];
    const float* n1b   = (const float*)d_in[5];
    const float* qkvw  = (const float*)d_in[6];
    const float* qkvb  = (const float*)d_in[7];
    const float* rpb   = (const float*)d_in[8];
    const float* projw = (const float*)d_in[9];
    const float* projb = (const float*)d_in[10];
    const float* n2g   = (const float*)d_in[11];
    const float* n2b   = (const float*)d_in[12];
    const float* fc1w  = (const float*)d_in[13];
    const float* fc1b  = (const float*)d_in[14];
    const float* fc2w  = (const float*)d_in[15];
    const float* fc2b  = (const float*)d_in[16];

    char* ws = (char*)d_ws;
    unsigned short* wt_qkv  = (unsigned short*)ws;          // 110592 elems
    unsigned short* wt_proj = wt_qkv + 110592;              // 36864
    unsigned short* wt_fc1  = wt_proj + 36864;              // 73728
    unsigned short* wt_fc2  = wt_fc1 + 73728;               // 73728
    float*          bt      = (float*)(ws + 589824);        // 884736 f32
    unsigned short* xn      = (unsigned short*)(ws + 4128768);   // 36864*192 bf16
    unsigned short* qkv     = (unsigned short*)(ws + 18284544);  // 36864*576 bf16
    unsigned short* attn_o  = (unsigned short*)(ws + 60751872);  // 36864*192 bf16
    float* outf = (float*)d_out;

    wcast_kernel<<<(110592 + 255) / 256, 256, 0, stream>>>(qkvw, wt_qkv, 192, 576);
    wcast_kernel<<<(36864 + 255) / 256, 256, 0, stream>>>(projw, wt_proj, 192, 192);
    wcast_kernel<<<(73728 + 255) / 256, 256, 0, stream>>>(fc1w, wt_fc1, 192, 384);
    wcast_kernel<<<(73728 + 255) / 256, 256, 0, stream>>>(fc2w, wt_fc2, 384, 192);
    biast_kernel<<<(884736 + 255) / 256, 256, 0, stream>>>(rpi, rpb, bt);
    ln_kernel<<<M_TOK / 4, 256, 0, stream>>>(x, n1g, n1b, xn);
    gemm_kernel<0><<<dim3(576 / 64, M_TOK / 128), 256, 0, stream>>>(
        xn, wt_qkv, qkvb, nullptr, qkv, M_TOK, 576, 192);
    attn_kernel<<<dim3(144, 6), 256, 0, stream>>>(qkv, bt, attn_o);
    gemm_kernel<1><<<dim3(192 / 64, M_TOK / 128), 256, 0, stream>>>(
        attn_o, wt_proj, projb, x, d_out, M_TOK, 192, 192);
    ln_kernel<<<M_TOK / 4, 256, 0, stream>>>(outf, n2g, n2b, xn);
    gemm_kernel<2><<<dim3(384 / 64, M_TOK / 128), 256, 0, stream>>>(
        xn, wt_fc1, fc1b, nullptr, qkv, M_TOK, 384, 192);
    gemm_kernel<3><<<dim3(192 / 64, M_TOK / 128), 256, 0, stream>>>(
        qkv, wt_fc2, fc2b, nullptr, d_out, M_TOK, 192, 384);
}

// Round 2
// 215.267 us; speedup vs baseline: 4.4100x; 4.4100x over previous
//
#include <hip/hip_runtime.h>
#include <hip/hip_bf16.h>

#define NH 6
#define DIM 192
#define HW 192
#define M_TOK (HW*HW)
#define SCALE 0.17677669529663689f

typedef __attribute__((ext_vector_type(8))) __bf16 bf16x8;
typedef __attribute__((ext_vector_type(8))) short short8;
typedef __attribute__((ext_vector_type(4))) float floatx4;

__device__ inline unsigned short f2bf(float f) {
    union { float f; unsigned int u; } v; v.f = f;
    unsigned int r = (v.u + 0x7FFFu + ((v.u >> 16) & 1u)) >> 16;
    return (unsigned short)r;
}
__device__ inline float bf2f(unsigned short h) {
    union { unsigned int u; float f; } v; v.u = ((unsigned int)h) << 16;
    return v.f;
}
__device__ inline short f2bfh(float f) {
    __bf16 b = (__bf16)f;
    return __builtin_bit_cast(short, b);
}

__device__ inline floatx4 mfma16(short8 a, short8 b, floatx4 c) {
    return __builtin_amdgcn_mfma_f32_16x16x32_bf16(
        __builtin_bit_cast(bf16x8, a), __builtin_bit_cast(bf16x8, b), c, 0, 0, 0);
}

// ---- cast + transpose weight: w (K x N) f32 -> wt (N x K) bf16 ----
__global__ void wcast_kernel(const float* __restrict__ w, unsigned short* __restrict__ wt,
                             int K, int N) {
    int id = blockIdx.x * 256 + threadIdx.x;
    if (id >= K * N) return;
    int n = id / K, k = id - n * K;
    wt[id] = f2bf(w[k * N + n]);
}

// ---- expand rel-pos bias into MFMA D-fragment order, pre-divided by SCALE ----
// btf[(((hh*16+qt)*36+kt)*64+lane)*4 + r] = bias[q=qt*16+(lane>>4)*4+r][k=kt*16+(lane&15)] / SCALE
__global__ void btfrag_kernel(const int* __restrict__ rpi, const float* __restrict__ table,
                              float* __restrict__ btf) {
    int id = blockIdx.x * 256 + threadIdx.x;   // 221184 total
    if (id >= 221184) return;
    int lane = id & 63;
    int t = id >> 6;
    int kt = t % 36; t /= 36;
    int qt = t & 15; int hh = t >> 4;
    int k = kt * 16 + (lane & 15);
    int qb = qt * 16 + (lane >> 4) * 4;
    floatx4 v;
    #pragma unroll
    for (int r = 0; r < 4; r++)
        v[r] = table[rpi[(qb + r) * 576 + k] * NH + hh] * 5.65685424949238f;
    *(floatx4*)&btf[(size_t)id * 4] = v;
}

// ---- LayerNorm: f32 in -> bf16 out, one wave per row of 192 ----
__global__ __launch_bounds__(256) void ln_kernel(const float* __restrict__ in,
                                                 const float* __restrict__ g,
                                                 const float* __restrict__ b,
                                                 unsigned short* __restrict__ out) {
    int row = blockIdx.x * 4 + (threadIdx.x >> 6);
    int lane = threadIdx.x & 63;
    const float* r = in + (size_t)row * DIM;
    float x0 = r[lane], x1 = r[lane + 64], x2 = r[lane + 128];
    float s = x0 + x1 + x2;
    #pragma unroll
    for (int m = 32; m >= 1; m >>= 1) s += __shfl_xor(s, m);
    float mean = s * (1.f / 192.f);
    float d0 = x0 - mean, d1 = x1 - mean, d2 = x2 - mean;
    float v = d0 * d0 + d1 * d1 + d2 * d2;
    #pragma unroll
    for (int m = 32; m >= 1; m >>= 1) v += __shfl_xor(v, m);
    float rstd = rsqrtf(v * (1.f / 192.f) + 1e-5f);
    unsigned short* o = out + (size_t)row * DIM;
    o[lane]       = f2bf(d0 * rstd * g[lane]       + b[lane]);
    o[lane + 64]  = f2bf(d1 * rstd * g[lane + 64]  + b[lane + 64]);
    o[lane + 128] = f2bf(d2 * rstd * g[lane + 128] + b[lane + 128]);
}

// ---- generic bf16 MFMA GEMM: A (M x K) @ Wt^T (Wt is N x K) + bias ----
template <int MODE>
__global__ __launch_bounds__(256, 2) void gemm_kernel(
    const unsigned short* __restrict__ A,
    const unsigned short* __restrict__ Wt,
    const float* __restrict__ bias,
    const float* __restrict__ res,
    void* __restrict__ outp,
    int M, int N, int K) {
    __shared__ short sA[128 * 72];
    __shared__ short sB[64 * 72];
    int tid = threadIdx.x;
    int bn = blockIdx.x, bm = blockIdx.y;
    int w = tid >> 6, lane = tid & 63;
    int lr = lane & 15, lk = (lane >> 4) * 8;
    floatx4 acc[2][4];
    #pragma unroll
    for (int i = 0; i < 2; i++)
        #pragma unroll
        for (int j = 0; j < 4; j++) acc[i][j] = (floatx4){0.f, 0.f, 0.f, 0.f};

    int tr = tid >> 3, tc = (tid & 7) * 8;
    const size_t abase = (size_t)(bm * 128) * K;
    const size_t bbase = (size_t)(bn * 64) * K;

    for (int k0 = 0; k0 < K; k0 += 64) {
        if (k0) __syncthreads();
        #pragma unroll
        for (int p = 0; p < 4; p++) {
            int row = p * 32 + tr;
            *(short8*)&sA[row * 72 + tc] =
                *(const short8*)&A[abase + (size_t)row * K + k0 + tc];
        }
        #pragma unroll
        for (int p = 0; p < 2; p++) {
            int row = p * 32 + tr;
            *(short8*)&sB[row * 72 + tc] =
                *(const short8*)&Wt[bbase + (size_t)row * K + k0 + tc];
        }
        __syncthreads();
        #pragma unroll
        for (int kk = 0; kk < 2; kk++) {
            short8 a0 = *(short8*)&sA[(w * 32 + lr) * 72 + kk * 32 + lk];
            short8 a1 = *(short8*)&sA[(w * 32 + 16 + lr) * 72 + kk * 32 + lk];
            short8 b0 = *(short8*)&sB[(lr) * 72 + kk * 32 + lk];
            short8 b1 = *(short8*)&sB[(16 + lr) * 72 + kk * 32 + lk];
            short8 b2 = *(short8*)&sB[(32 + lr) * 72 + kk * 32 + lk];
            short8 b3 = *(short8*)&sB[(48 + lr) * 72 + kk * 32 + lk];
            acc[0][0] = mfma16(a0, b0, acc[0][0]);
            acc[0][1] = mfma16(a0, b1, acc[0][1]);
            acc[0][2] = mfma16(a0, b2, acc[0][2]);
            acc[0][3] = mfma16(a0, b3, acc[0][3]);
            acc[1][0] = mfma16(a1, b0, acc[1][0]);
            acc[1][1] = mfma16(a1, b1, acc[1][1]);
            acc[1][2] = mfma16(a1, b2, acc[1][2]);
            acc[1][3] = mfma16(a1, b3, acc[1][3]);
        }
    }

    int rowbase = bm * 128 + w * 32 + (lane >> 4) * 4;
    int colbase = bn * 64;
    #pragma unroll
    for (int mi = 0; mi < 2; mi++) {
        #pragma unroll
        for (int ni = 0; ni < 4; ni++) {
            int c = colbase + ni * 16 + lr;
            float bv = bias[c];
            #pragma unroll
            for (int j = 0; j < 4; j++) {
                int r = rowbase + mi * 16 + j;
                size_t idx = (size_t)r * N + c;
                float v = acc[mi][ni][j] + bv;
                if (MODE == 0) {
                    ((unsigned short*)outp)[idx] = f2bf(v);
                } else if (MODE == 1) {
                    ((float*)outp)[idx] = v + res[idx];
                } else if (MODE == 2) {
                    float gl = 0.5f * v * (1.f + erff(v * 0.70710678118654752f));
                    ((unsigned short*)outp)[idx] = f2bf(gl);
                } else {
                    ((float*)outp)[idx] = v + ((float*)outp)[idx];
                }
            }
        }
    }
}

// ---- MFMA windowed attention: one block per (window, head), 4 waves ----
// Wave w owns q-rows wy = 4w..4w+3 (each q-tile = one window row of 16 queries).
// K chunks of 64 keys; K in sK[key][dim] (stride 36), V in sVt[dim][key] (stride 68),
// P round-trips through per-wave sP[q][k] (stride 68, conflict-free u16 writes).
__global__ __launch_bounds__(256, 2) void attn_mfma_kernel(
    const unsigned short* __restrict__ qkv,
    const float* __restrict__ btf,
    unsigned short* __restrict__ out) {
    __shared__ short sK[64 * 36];
    __shared__ short sVt[32 * 68];
    __shared__ short sP[4][64 * 68];
    int win = blockIdx.x, head = blockIdx.y;
    int iy = win / 12, ix = win % 12;
    int tid = threadIdx.x;
    int w = tid >> 6, lane = tid & 63;
    int m = lane & 15, h = lane >> 4;

    // Q fragments: A-layout, row = m (query x), k-dim = 8h+j (head dims)
    short8 qf[4];
    #pragma unroll
    for (int i = 0; i < 4; i++) {
        int wy = w * 4 + i;
        size_t tok = (size_t)(iy * 16 + wy) * HW + ix * 16 + m;
        qf[i] = *(const short8*)&qkv[tok * 576 + head * 32 + h * 8];
    }

    short ob = (m == 0) ? (short)0x3F80 : (short)0;
    short8 bones = {ob, ob, ob, ob, ob, ob, ob, ob};

    floatx4 oacc[4][2];
    floatx4 lacc[4];
    #pragma unroll
    for (int i = 0; i < 4; i++) {
        lacc[i] = (floatx4){0.f, 0.f, 0.f, 0.f};
        #pragma unroll
        for (int dt = 0; dt < 2; dt++) oacc[i][dt] = (floatx4){0.f, 0.f, 0.f, 0.f};
    }

    short* sPw = sP[w];

    for (int c = 0; c < 9; c++) {
        __syncthreads();
        {   // stage 64 keys: 4 threads per key, each 8 dims
            int key = c * 64 + (tid >> 2);
            int dq = tid & 3;
            int oy = key / 24, ox = key - (key / 24) * 24;
            int gy = iy * 16 - 4 + oy, gx = ix * 16 - 4 + ox;
            short8 kv = (short8){0, 0, 0, 0, 0, 0, 0, 0};
            short8 vv = (short8){0, 0, 0, 0, 0, 0, 0, 0};
            if (gy >= 0 && gy < HW && gx >= 0 && gx < HW) {
                size_t base = ((size_t)gy * HW + gx) * 576 + head * 32 + dq * 8;
                kv = *(const short8*)&qkv[base + 192];
                vv = *(const short8*)&qkv[base + 384];
            }
            int kk = tid >> 2;
            *(short8*)&sK[kk * 36 + dq * 8] = kv;
            #pragma unroll
            for (int j = 0; j < 8; j++) sVt[(dq * 8 + j) * 68 + kk] = vv[j];
        }
        __syncthreads();

        // ---- S = Q K^T + bias (C-init from btf) ----
        floatx4 s[4][4];
        const float* bb = &btf[((((size_t)head * 16 + w * 4) * 36 + c * 4) * 64 + lane) * 4];
        #pragma unroll
        for (int i = 0; i < 4; i++)
            #pragma unroll
            for (int kt = 0; kt < 4; kt++)
                s[i][kt] = *(const floatx4*)&bb[(size_t)(i * 36 + kt) * 256];
        short8 kfrag[4];
        #pragma unroll
        for (int kt = 0; kt < 4; kt++)
            kfrag[kt] = *(short8*)&sK[(kt * 16 + m) * 36 + h * 8];
        #pragma unroll
        for (int i = 0; i < 4; i++)
            #pragma unroll
            for (int kt = 0; kt < 4; kt++)
                s[i][kt] = mfma16(qf[i], kfrag[kt], s[i][kt]);

        // ---- P = exp(S*scale), write bf16 to per-wave sP ----
        #pragma unroll
        for (int i = 0; i < 4; i++)
            #pragma unroll
            for (int kt = 0; kt < 4; kt++)
                #pragma unroll
                for (int r = 0; r < 4; r++) {
                    float p = __expf(s[i][kt][r] * SCALE);
                    sPw[(i * 16 + h * 4 + r) * 68 + kt * 16 + m] = f2bfh(p);
                }

        // ---- O += P V, L += P 1 ----
        #pragma unroll
        for (int g = 0; g < 2; g++) {
            short8 pa[4], vb[2];
            #pragma unroll
            for (int i = 0; i < 4; i++)
                pa[i] = *(short8*)&sPw[(i * 16 + m) * 68 + g * 32 + h * 8];
            #pragma unroll
            for (int dt = 0; dt < 2; dt++)
                vb[dt] = *(short8*)&sVt[(dt * 16 + m) * 68 + g * 32 + h * 8];
            #pragma unroll
            for (int i = 0; i < 4; i++) {
                #pragma unroll
                for (int dt = 0; dt < 2; dt++)
                    oacc[i][dt] = mfma16(pa[i], vb[dt], oacc[i][dt]);
                lacc[i] = mfma16(pa[i], bones, lacc[i]);
            }
        }
    }

    // ---- normalize + store ----
    #pragma unroll
    for (int i = 0; i < 4; i++) {
        float inv[4];
        #pragma unroll
        for (int r = 0; r < 4; r++) {
            float sum = __shfl(lacc[i][r], lane & 48);
            inv[r] = 1.f / sum;
        }
        int wy = w * 4 + i;
        #pragma unroll
        for (int dt = 0; dt < 2; dt++)
            #pragma unroll
            for (int r = 0; r < 4; r++) {
                size_t tok = (size_t)(iy * 16 + wy) * HW + ix * 16 + h * 4 + r;
                out[tok * DIM + head * 32 + dt * 16 + m] = f2bf(oacc[i][dt][r] * inv[r]);
            }
    }
}

extern "C" void kernel_launch(void* const* d_in, const int* in_sizes, int n_in,
                              void* d_out, int out_size, void* d_ws, size_t ws_size,
                              hipStream_t stream) {
    const float* x     = (const float*)d_in[0];
    const int*   rpi   = (const int*)d_in[1];
    const float* n1g   = (const float*)d_in[4];
    const float* n1b   = (const float*)d_in[5];
    const float* qkvw  = (const float*)d_in[6];
    const float* qkvb  = (const float*)d_in[7];
    const float* rpb   = (const float*)d_in[8];
    const float* projw = (const float*)d_in[9];
    const float* projb = (const float*)d_in[10];
    const float* n2g   = (const float*)d_in[11];
    const float* n2b   = (const float*)d_in[12];
    const float* fc1w  = (const float*)d_in[13];
    const float* fc1b  = (const float*)d_in[14];
    const float* fc2w  = (const float*)d_in[15];
    const float* fc2b  = (const float*)d_in[16];

    char* ws = (char*)d_ws;
    unsigned short* wt_qkv  = (unsigned short*)ws;          // 110592 elems
    unsigned short* wt_proj = wt_qkv + 110592;              // 36864
    unsigned short* wt_fc1  = wt_proj + 36864;              // 73728
    unsigned short* wt_fc2  = wt_fc1 + 73728;               // 73728
    float*          btf     = (float*)(ws + 589824);        // 884736 f32 (frag-order bias)
    unsigned short* xn      = (unsigned short*)(ws + 4128768);   // 36864*192 bf16
    unsigned short* qkv     = (unsigned short*)(ws + 18284544);  // 36864*576 bf16
    unsigned short* attn_o  = (unsigned short*)(ws + 60751872);  // 36864*192 bf16
    float* outf = (float*)d_out;

    wcast_kernel<<<(110592 + 255) / 256, 256, 0, stream>>>(qkvw, wt_qkv, 192, 576);
    wcast_kernel<<<(36864 + 255) / 256, 256, 0, stream>>>(projw, wt_proj, 192, 192);
    wcast_kernel<<<(73728 + 255) / 256, 256, 0, stream>>>(fc1w, wt_fc1, 192, 384);
    wcast_kernel<<<(73728 + 255) / 256, 256, 0, stream>>>(fc2w, wt_fc2, 384, 192);
    btfrag_kernel<<<(221184 + 255) / 256, 256, 0, stream>>>(rpi, rpb, btf);
    ln_kernel<<<M_TOK / 4, 256, 0, stream>>>(x, n1g, n1b, xn);
    gemm_kernel<0><<<dim3(576 / 64, M_TOK / 128), 256, 0, stream>>>(
        xn, wt_qkv, qkvb, nullptr, qkv, M_TOK, 576, 192);
    attn_mfma_kernel<<<dim3(144, 6), 256, 0, stream>>>(qkv, btf, attn_o);
    gemm_kernel<1><<<dim3(192 / 64, M_TOK / 128), 256, 0, stream>>>(
        attn_o, wt_proj, projb, x, d_out, M_TOK, 192, 192);
    ln_kernel<<<M_TOK / 4, 256, 0, stream>>>(outf, n2g, n2b, xn);
    gemm_kernel<2><<<dim3(384 / 64, M_TOK / 128), 256, 0, stream>>>(
        xn, wt_fc1, fc1b, nullptr, qkv, M_TOK, 384, 192);
    gemm_kernel<3><<<dim3(192 / 64, M_TOK / 128), 256, 0, stream>>>(
        qkv, wt_fc2, fc2b, nullptr, d_out, M_TOK, 192, 384);
}

// Round 3
// 200.001 us; speedup vs baseline: 4.7466x; 1.0763x over previous
//
#include <hip/hip_runtime.h>
#include <hip/hip_bf16.h>

#define NH 6
#define DIM 192
#define HW 192
#define M_TOK (HW*HW)
// SCALE*log2e and log2e
#define QSC 0.25503488f
#define L2E 1.4426950408889634f

typedef __attribute__((ext_vector_type(8))) __bf16 bf16x8;
typedef __attribute__((ext_vector_type(8))) short short8;
typedef __attribute__((ext_vector_type(4))) short s16x4;
typedef __attribute__((ext_vector_type(4))) float floatx4;

__device__ inline unsigned short f2bf(float f) {
    union { float f; unsigned int u; } v; v.f = f;
    unsigned int r = (v.u + 0x7FFFu + ((v.u >> 16) & 1u)) >> 16;
    return (unsigned short)r;
}
__device__ inline short f2bfh(float f) {
    __bf16 b = (__bf16)f;
    return __builtin_bit_cast(short, b);
}
__device__ inline float exp2fast(float x) {
#if __has_builtin(__builtin_amdgcn_exp2f)
    return __builtin_amdgcn_exp2f(x);
#else
    return exp2f(x);
#endif
}

__device__ inline floatx4 mfma16(short8 a, short8 b, floatx4 c) {
    return __builtin_amdgcn_mfma_f32_16x16x32_bf16(
        __builtin_bit_cast(bf16x8, a), __builtin_bit_cast(bf16x8, b), c, 0, 0, 0);
}

template <int OFF>
__device__ inline s16x4 tr16(unsigned addr) {
    s16x4 r;
    asm volatile("ds_read_b64_tr_b16 %0, %1 offset:%2"
                 : "=&v"(r) : "v"(addr), "i"(OFF));
    return r;
}
template <int OFF>
__device__ inline s16x4 tr16m(unsigned addr) {
    s16x4 r;
    asm volatile("ds_read_b64_tr_b16 %0, %1 offset:%2"
                 : "=&v"(r) : "v"(addr), "i"(OFF) : "memory");
    return r;
}
__device__ inline short8 cat8(s16x4 a, s16x4 b) {
    return __builtin_shufflevector(a, b, 0, 1, 2, 3, 4, 5, 6, 7);
}

// ---- cast + transpose weight: w (K x N) f32 -> wt (N x K) bf16 ----
__global__ void wcast_kernel(const float* __restrict__ w, unsigned short* __restrict__ wt,
                             int K, int N) {
    int id = blockIdx.x * 256 + threadIdx.x;
    if (id >= K * N) return;
    int n = id / K, k = id - n * K;
    wt[id] = f2bf(w[k * N + n]);
}

// ---- expand rel-pos bias into MFMA D-fragment order, pre-multiplied by log2e ----
__global__ void btfrag_kernel(const int* __restrict__ rpi, const float* __restrict__ table,
                              float* __restrict__ btf) {
    int id = blockIdx.x * 256 + threadIdx.x;   // 221184 total
    if (id >= 221184) return;
    int lane = id & 63;
    int t = id >> 6;
    int kt = t % 36; t /= 36;
    int qt = t & 15; int hh = t >> 4;
    int k = kt * 16 + (lane & 15);
    int qb = qt * 16 + (lane >> 4) * 4;
    floatx4 v;
    #pragma unroll
    for (int r = 0; r < 4; r++)
        v[r] = table[rpi[(qb + r) * 576 + k] * NH + hh] * L2E;
    *(floatx4*)&btf[(size_t)id * 4] = v;
}

// ---- LayerNorm: f32 in -> bf16 out, one wave per row of 192 ----
__global__ __launch_bounds__(256) void ln_kernel(const float* __restrict__ in,
                                                 const float* __restrict__ g,
                                                 const float* __restrict__ b,
                                                 unsigned short* __restrict__ out) {
    int row = blockIdx.x * 4 + (threadIdx.x >> 6);
    int lane = threadIdx.x & 63;
    const float* r = in + (size_t)row * DIM;
    float x0 = r[lane], x1 = r[lane + 64], x2 = r[lane + 128];
    float s = x0 + x1 + x2;
    #pragma unroll
    for (int m = 32; m >= 1; m >>= 1) s += __shfl_xor(s, m);
    float mean = s * (1.f / 192.f);
    float d0 = x0 - mean, d1 = x1 - mean, d2 = x2 - mean;
    float v = d0 * d0 + d1 * d1 + d2 * d2;
    #pragma unroll
    for (int m = 32; m >= 1; m >>= 1) v += __shfl_xor(v, m);
    float rstd = rsqrtf(v * (1.f / 192.f) + 1e-5f);
    unsigned short* o = out + (size_t)row * DIM;
    o[lane]       = f2bf(d0 * rstd * g[lane]       + b[lane]);
    o[lane + 64]  = f2bf(d1 * rstd * g[lane + 64]  + b[lane + 64]);
    o[lane + 128] = f2bf(d2 * rstd * g[lane + 128] + b[lane + 128]);
}

// ---- generic bf16 MFMA GEMM: A (M x K) @ Wt^T (Wt is N x K) + bias ----
// MODE 0: out bf16 = acc + bias, cols<192 scaled by QSC (qkv: pre-scale Q)
// MODE 1: out f32  = acc + bias + res           (proj + shortcut)
// MODE 2: out bf16 = gelu(acc + bias)           (fc1)
// MODE 3: out f32  = acc + bias + out (in-place) (fc2 + x2)
template <int MODE>
__global__ __launch_bounds__(256, 2) void gemm_kernel(
    const unsigned short* __restrict__ A,
    const unsigned short* __restrict__ Wt,
    const float* __restrict__ bias,
    const float* __restrict__ res,
    void* __restrict__ outp,
    int M, int N, int K) {
    __shared__ short sA[128 * 72];
    __shared__ short sB[64 * 72];
    int tid = threadIdx.x;
    int bn = blockIdx.x, bm = blockIdx.y;
    int w = tid >> 6, lane = tid & 63;
    int lr = lane & 15, lk = (lane >> 4) * 8;
    floatx4 acc[2][4];
    #pragma unroll
    for (int i = 0; i < 2; i++)
        #pragma unroll
        for (int j = 0; j < 4; j++) acc[i][j] = (floatx4){0.f, 0.f, 0.f, 0.f};

    int tr = tid >> 3, tc = (tid & 7) * 8;
    const size_t abase = (size_t)(bm * 128) * K;
    const size_t bbase = (size_t)(bn * 64) * K;

    for (int k0 = 0; k0 < K; k0 += 64) {
        if (k0) __syncthreads();
        #pragma unroll
        for (int p = 0; p < 4; p++) {
            int row = p * 32 + tr;
            *(short8*)&sA[row * 72 + tc] =
                *(const short8*)&A[abase + (size_t)row * K + k0 + tc];
        }
        #pragma unroll
        for (int p = 0; p < 2; p++) {
            int row = p * 32 + tr;
            *(short8*)&sB[row * 72 + tc] =
                *(const short8*)&Wt[bbase + (size_t)row * K + k0 + tc];
        }
        __syncthreads();
        #pragma unroll
        for (int kk = 0; kk < 2; kk++) {
            short8 a0 = *(short8*)&sA[(w * 32 + lr) * 72 + kk * 32 + lk];
            short8 a1 = *(short8*)&sA[(w * 32 + 16 + lr) * 72 + kk * 32 + lk];
            short8 b0 = *(short8*)&sB[(lr) * 72 + kk * 32 + lk];
            short8 b1 = *(short8*)&sB[(16 + lr) * 72 + kk * 32 + lk];
            short8 b2 = *(short8*)&sB[(32 + lr) * 72 + kk * 32 + lk];
            short8 b3 = *(short8*)&sB[(48 + lr) * 72 + kk * 32 + lk];
            acc[0][0] = mfma16(a0, b0, acc[0][0]);
            acc[0][1] = mfma16(a0, b1, acc[0][1]);
            acc[0][2] = mfma16(a0, b2, acc[0][2]);
            acc[0][3] = mfma16(a0, b3, acc[0][3]);
            acc[1][0] = mfma16(a1, b0, acc[1][0]);
            acc[1][1] = mfma16(a1, b1, acc[1][1]);
            acc[1][2] = mfma16(a1, b2, acc[1][2]);
            acc[1][3] = mfma16(a1, b3, acc[1][3]);
        }
    }

    int rowbase = bm * 128 + w * 32 + (lane >> 4) * 4;
    int colbase = bn * 64;
    #pragma unroll
    for (int mi = 0; mi < 2; mi++) {
        #pragma unroll
        for (int ni = 0; ni < 4; ni++) {
            int c = colbase + ni * 16 + lr;
            float bv = bias[c];
            #pragma unroll
            for (int j = 0; j < 4; j++) {
                int r = rowbase + mi * 16 + j;
                size_t idx = (size_t)r * N + c;
                float v = acc[mi][ni][j] + bv;
                if (MODE == 0) {
                    if (c < 192) v *= QSC;
                    ((unsigned short*)outp)[idx] = f2bf(v);
                } else if (MODE == 1) {
                    ((float*)outp)[idx] = v + res[idx];
                } else if (MODE == 2) {
                    float gl = 0.5f * v * (1.f + erff(v * 0.70710678118654752f));
                    ((unsigned short*)outp)[idx] = f2bf(gl);
                } else {
                    ((float*)outp)[idx] = v + ((float*)outp)[idx];
                }
            }
        }
    }
}

// ---- MFMA windowed attention, tr-read edition ----
// Block = (window, head), 4 waves; wave w owns q-tiles i = w*4..w*4+3.
// K: [buf][key][dim] stride 36 (b128 stage + b128 B-frag reads).
// V: [buf] tr-subtiled: elem = (dq>>1)*1024 + (key>>2)*64 + (key&3)*16 + (d&15);
//    staged with one b128 write, consumed by ds_read_b64_tr_b16.
// P: per-wave tr-subtiled [key>>2][key&3][q]: D-frag's 4 q-contiguous values ->
//    one b64 write per kt; A-frags read back via tr reads.
__global__ __launch_bounds__(256, 3) void attn_mfma_kernel(
    const unsigned short* __restrict__ qkv,
    const float* __restrict__ btf,
    unsigned short* __restrict__ out) {
    __shared__ __align__(16) short sK[2][64 * 36];
    __shared__ __align__(16) short sV[2][2048];
    __shared__ __align__(16) short sPt[4][1024];
    int win = blockIdx.x, head = blockIdx.y;
    int iy = win / 12, ix = win % 12;
    int tid = threadIdx.x;
    int w = tid >> 6, lane = tid & 63;
    int m = lane & 15, h = lane >> 4;

    // Q fragments (already scaled by SCALE*log2e in the qkv GEMM epilogue)
    short8 qf[4];
    #pragma unroll
    for (int i = 0; i < 4; i++) {
        int wy = w * 4 + i;
        size_t tok = (size_t)(iy * 16 + wy) * HW + ix * 16 + m;
        qf[i] = *(const short8*)&qkv[tok * 576 + head * 32 + h * 8];
    }

    short ob = (m == 0) ? (short)0x3F80 : (short)0;
    short8 bones = {ob, ob, ob, ob, ob, ob, ob, ob};

    floatx4 oacc[4][2];
    floatx4 lacc[4];
    #pragma unroll
    for (int i = 0; i < 4; i++) {
        lacc[i] = (floatx4){0.f, 0.f, 0.f, 0.f};
        oacc[i][0] = (floatx4){0.f, 0.f, 0.f, 0.f};
        oacc[i][1] = (floatx4){0.f, 0.f, 0.f, 0.f};
    }

    // staging mapping: 4 threads per key, 8 dims each
    int skey = tid >> 2, dq = tid & 3;
    short* kdst = &sK[0][skey * 36 + dq * 8];
    short* vdst = &sV[0][(dq >> 1) * 1024 + (skey >> 2) * 64 + (skey & 3) * 16 + (dq & 1) * 8];

    auto fetch = [&](int c, short8& kv, short8& vv) {
        int key = c * 64 + skey;
        int oy = key / 24, ox = key - (key / 24) * 24;
        int gy = iy * 16 - 4 + oy, gx = ix * 16 - 4 + ox;
        kv = (short8){0,0,0,0,0,0,0,0};
        vv = (short8){0,0,0,0,0,0,0,0};
        if (gy >= 0 && gy < HW && gx >= 0 && gx < HW) {
            const unsigned short* p = &qkv[((size_t)gy * HW + gx) * 576 + 192 + head * 32 + dq * 8];
            kv = *(const short8*)p;
            vv = *(const short8*)(p + 192);
        }
    };

    {   // stage chunk 0 into buffer 0
        short8 kv, vv;
        fetch(0, kv, vv);
        *(short8*)kdst = kv;
        *(short8*)vdst = vv;
    }

    // tr-read per-lane addresses (byte): base + 8*(l&15) + 256*(l>>4)
    unsigned sPa = (unsigned)(uintptr_t)&sPt[w][0] + 8 * m + 256 * h;
    unsigned sVa0 = (unsigned)(uintptr_t)&sV[0][0] + 8 * m + 256 * h;
    // P write base (byte): 128*(m>>2) + 32*(m&3) + 8*h  (+512*kt imm)
    char* sPw = (char*)&sPt[w][0] + 128 * (m >> 2) + 32 * (m & 3) + 8 * h;

    for (int c = 0; c < 9; c++) {
        __syncthreads();
        int cur = c & 1;
        short8 knx, vnx;
        bool more = (c < 8);
        if (more) fetch(c + 1, knx, vnx);   // loads in flight during compute

        const short* sKc = sK[cur];
        unsigned sVa = sVa0 + cur * 4096;

        short8 kfrag[4];
        #pragma unroll
        for (int kt = 0; kt < 4; kt++)
            kfrag[kt] = *(const short8*)&sKc[(kt * 16 + m) * 36 + h * 8];

        // V B-frags via tr reads: vb[g*2+dt], keys g*32+8h+j, d=dt*16+m
        short8 vb[4];
        {
            s16x4 lo0 = tr16<0>(sVa),          hi0 = tr16<128>(sVa);
            s16x4 lo1 = tr16<2048>(sVa),       hi1 = tr16<2176>(sVa);
            s16x4 lo2 = tr16<1024>(sVa),       hi2 = tr16<1152>(sVa);
            s16x4 lo3 = tr16<3072>(sVa),       hi3 = tr16<3200>(sVa);
            vb[0] = cat8(lo0, hi0);
            vb[1] = cat8(lo1, hi1);
            vb[2] = cat8(lo2, hi2);
            vb[3] = cat8(lo3, hi3);
        }

        const float* bb = btf + ((((size_t)head * 16 + w * 4) * 36 + c * 4) * 64 + lane) * 4;

        #pragma unroll
        for (int i = 0; i < 4; i++) {
            floatx4 s[4];
            #pragma unroll
            for (int kt = 0; kt < 4; kt++)
                s[kt] = *(const floatx4*)&bb[(size_t)(i * 36 + kt) * 256];
            #pragma unroll
            for (int kt = 0; kt < 4; kt++)
                s[kt] = mfma16(qf[i], kfrag[kt], s[kt]);

            // P = exp2(S): pack 4 q-contiguous bf16, one b64 write per kt
            #pragma unroll
            for (int kt = 0; kt < 4; kt++) {
                s16x4 pk;
                #pragma unroll
                for (int r = 0; r < 4; r++)
                    pk[r] = f2bfh(exp2fast(s[kt][r]));
                *(s16x4*)(sPw + 512 * kt) = pk;
            }

            // P A-frags via tr reads (same-wave DS ordering; "memory" pins order)
            s16x4 plo0 = tr16m<0>(sPa),    phi0 = tr16m<128>(sPa);
            s16x4 plo1 = tr16m<1024>(sPa), phi1 = tr16m<1152>(sPa);
            asm volatile("s_waitcnt lgkmcnt(0)" ::: "memory");
            __builtin_amdgcn_sched_barrier(0);
            short8 pa0 = cat8(plo0, phi0);
            short8 pa1 = cat8(plo1, phi1);

            oacc[i][0] = mfma16(pa0, vb[0], oacc[i][0]);
            oacc[i][1] = mfma16(pa0, vb[1], oacc[i][1]);
            oacc[i][0] = mfma16(pa1, vb[2], oacc[i][0]);
            oacc[i][1] = mfma16(pa1, vb[3], oacc[i][1]);
            lacc[i] = mfma16(pa0, bones, lacc[i]);
            lacc[i] = mfma16(pa1, bones, lacc[i]);
        }

        if (more) {   // write prefetched chunk into the other buffer
            int nb = 1 - cur;
            *(short8*)(kdst + nb * 2304) = knx;
            *(short8*)(vdst + nb * 2048) = vnx;
        }
    }

    // ---- normalize + store ----
    #pragma unroll
    for (int i = 0; i < 4; i++) {
        float inv[4];
        #pragma unroll
        for (int r = 0; r < 4; r++) {
            float sum = __shfl(lacc[i][r], lane & 48);
            inv[r] = 1.f / sum;
        }
        int wy = w * 4 + i;
        #pragma unroll
        for (int dt = 0; dt < 2; dt++)
            #pragma unroll
            for (int r = 0; r < 4; r++) {
                size_t tok = (size_t)(iy * 16 + wy) * HW + ix * 16 + h * 4 + r;
                out[tok * DIM + head * 32 + dt * 16 + m] = f2bf(oacc[i][dt][r] * inv[r]);
            }
    }
}

extern "C" void kernel_launch(void* const* d_in, const int* in_sizes, int n_in,
                              void* d_out, int out_size, void* d_ws, size_t ws_size,
                              hipStream_t stream) {
    const float* x     = (const float*)d_in[0];
    const int*   rpi   = (const int*)d_in[1];
    const float* n1g   = (const float*)d_in[4];
    const float* n1b   = (const float*)d_in[5];
    const float* qkvw  = (const float*)d_in[6];
    const float* qkvb  = (const float*)d_in[7];
    const float* rpb   = (const float*)d_in[8];
    const float* projw = (const float*)d_in[9];
    const float* projb = (const float*)d_in[10];
    const float* n2g   = (const float*)d_in[11];
    const float* n2b   = (const float*)d_in[12];
    const float* fc1w  = (const float*)d_in[13];
    const float* fc1b  = (const float*)d_in[14];
    const float* fc2w  = (const float*)d_in[15];
    const float* fc2b  = (const float*)d_in[16];

    char* ws = (char*)d_ws;
    unsigned short* wt_qkv  = (unsigned short*)ws;          // 110592 elems
    unsigned short* wt_proj = wt_qkv + 110592;              // 36864
    unsigned short* wt_fc1  = wt_proj + 36864;              // 73728
    unsigned short* wt_fc2  = wt_fc1 + 73728;               // 73728
    float*          btf     = (float*)(ws + 589824);        // 884736 f32 (frag-order bias)
    unsigned short* xn      = (unsigned short*)(ws + 4128768);   // 36864*192 bf16
    unsigned short* qkv     = (unsigned short*)(ws + 18284544);  // 36864*576 bf16
    unsigned short* attn_o  = (unsigned short*)(ws + 60751872);  // 36864*192 bf16
    float* outf = (float*)d_out;

    wcast_kernel<<<(110592 + 255) / 256, 256, 0, stream>>>(qkvw, wt_qkv, 192, 576);
    wcast_kernel<<<(36864 + 255) / 256, 256, 0, stream>>>(projw, wt_proj, 192, 192);
    wcast_kernel<<<(73728 + 255) / 256, 256, 0, stream>>>(fc1w, wt_fc1, 192, 384);
    wcast_kernel<<<(73728 + 255) / 256, 256, 0, stream>>>(fc2w, wt_fc2, 384, 192);
    btfrag_kernel<<<(221184 + 255) / 256, 256, 0, stream>>>(rpi, rpb, btf);
    ln_kernel<<<M_TOK / 4, 256, 0, stream>>>(x, n1g, n1b, xn);
    gemm_kernel<0><<<dim3(576 / 64, M_TOK / 128), 256, 0, stream>>>(
        xn, wt_qkv, qkvb, nullptr, qkv, M_TOK, 576, 192);
    attn_mfma_kernel<<<dim3(144, 6), 256, 0, stream>>>(qkv, btf, attn_o);
    gemm_kernel<1><<<dim3(192 / 64, M_TOK / 128), 256, 0, stream>>>(
        attn_o, wt_proj, projb, x, d_out, M_TOK, 192, 192);
    ln_kernel<<<M_TOK / 4, 256, 0, stream>>>(outf, n2g, n2b, xn);
    gemm_kernel<2><<<dim3(384 / 64, M_TOK / 128), 256, 0, stream>>>(
        xn, wt_fc1, fc1b, nullptr, qkv, M_TOK, 384, 192);
    gemm_kernel<3><<<dim3(192 / 64, M_TOK / 128), 256, 0, stream>>>(
        qkv, wt_fc2, fc2b, nullptr, d_out, M_TOK, 192, 384);
}

// Round 4
// 169.214 us; speedup vs baseline: 5.6102x; 1.1819x over previous
//
#include <hip/hip_runtime.h>
#include <hip/hip_bf16.h>

#define NH 6
#define DIM 192
#define HW 192
#define M_TOK (HW*HW)
// SCALE*log2e and log2e
#define QSC 0.25503488f
#define L2E 1.4426950408889634f

typedef __attribute__((ext_vector_type(8))) __bf16 bf16x8;
typedef __attribute__((ext_vector_type(8))) short short8;
typedef __attribute__((ext_vector_type(4))) short s16x4;
typedef __attribute__((ext_vector_type(4))) float floatx4;

__device__ inline unsigned short f2bf(float f) {
    union { float f; unsigned int u; } v; v.f = f;
    unsigned int r = (v.u + 0x7FFFu + ((v.u >> 16) & 1u)) >> 16;
    return (unsigned short)r;
}
__device__ inline short f2bfh(float f) {
    __bf16 b = (__bf16)f;
    return __builtin_bit_cast(short, b);
}
__device__ inline float exp2fast(float x) {
#if __has_builtin(__builtin_amdgcn_exp2f)
    return __builtin_amdgcn_exp2f(x);
#else
    return exp2f(x);
#endif
}

__device__ inline floatx4 mfma16(short8 a, short8 b, floatx4 c) {
    return __builtin_amdgcn_mfma_f32_16x16x32_bf16(
        __builtin_bit_cast(bf16x8, a), __builtin_bit_cast(bf16x8, b), c, 0, 0, 0);
}

template <int OFF>
__device__ inline s16x4 tr16(unsigned addr) {
    s16x4 r;
    asm volatile("ds_read_b64_tr_b16 %0, %1 offset:%2"
                 : "=&v"(r) : "v"(addr), "i"(OFF));
    return r;
}
template <int OFF>
__device__ inline s16x4 tr16m(unsigned addr) {
    s16x4 r;
    asm volatile("ds_read_b64_tr_b16 %0, %1 offset:%2"
                 : "=&v"(r) : "v"(addr), "i"(OFF) : "memory");
    return r;
}
template <int N>
__device__ __forceinline__ void wait_lgkm() {
    asm volatile("s_waitcnt lgkmcnt(%0)" :: "i"(N) : "memory");
}
__device__ inline short8 cat8(s16x4 a, s16x4 b) {
    return __builtin_shufflevector(a, b, 0, 1, 2, 3, 4, 5, 6, 7);
}

// async global->LDS, 16B per lane; lds_off = wave-uniform LDS byte offset
__device__ __forceinline__ void gload16(const void* g, unsigned lds_off) {
    __builtin_amdgcn_global_load_lds(
        (const __attribute__((address_space(1))) unsigned int*)(uintptr_t)g,
        (__attribute__((address_space(3))) unsigned int*)(uintptr_t)lds_off,
        16, 0, 0);
}

// ---- cast + transpose weight: w (K x N) f32 -> wt (N x K) bf16 ----
__global__ void wcast_kernel(const float* __restrict__ w, unsigned short* __restrict__ wt,
                             int K, int N) {
    int id = blockIdx.x * 256 + threadIdx.x;
    if (id >= K * N) return;
    int n = id / K, k = id - n * K;
    wt[id] = f2bf(w[k * N + n]);
}

// ---- expand rel-pos bias into MFMA D-fragment order, pre-multiplied by log2e ----
__global__ void btfrag_kernel(const int* __restrict__ rpi, const float* __restrict__ table,
                              float* __restrict__ btf) {
    int id = blockIdx.x * 256 + threadIdx.x;   // 221184 total
    if (id >= 221184) return;
    int lane = id & 63;
    int t = id >> 6;
    int kt = t % 36; t /= 36;
    int qt = t & 15; int hh = t >> 4;
    int k = kt * 16 + (lane & 15);
    int qb = qt * 16 + (lane >> 4) * 4;
    floatx4 v;
    #pragma unroll
    for (int r = 0; r < 4; r++)
        v[r] = table[rpi[(qb + r) * 576 + k] * NH + hh] * L2E;
    *(floatx4*)&btf[(size_t)id * 4] = v;
}

// ---- LayerNorm: f32 in -> bf16 out, one wave per row of 192 ----
__global__ __launch_bounds__(256) void ln_kernel(const float* __restrict__ in,
                                                 const float* __restrict__ g,
                                                 const float* __restrict__ b,
                                                 unsigned short* __restrict__ out) {
    int row = blockIdx.x * 4 + (threadIdx.x >> 6);
    int lane = threadIdx.x & 63;
    const float* r = in + (size_t)row * DIM;
    float x0 = r[lane], x1 = r[lane + 64], x2 = r[lane + 128];
    float s = x0 + x1 + x2;
    #pragma unroll
    for (int m = 32; m >= 1; m >>= 1) s += __shfl_xor(s, m);
    float mean = s * (1.f / 192.f);
    float d0 = x0 - mean, d1 = x1 - mean, d2 = x2 - mean;
    float v = d0 * d0 + d1 * d1 + d2 * d2;
    #pragma unroll
    for (int m = 32; m >= 1; m >>= 1) v += __shfl_xor(v, m);
    float rstd = rsqrtf(v * (1.f / 192.f) + 1e-5f);
    unsigned short* o = out + (size_t)row * DIM;
    o[lane]       = f2bf(d0 * rstd * g[lane]       + b[lane]);
    o[lane + 64]  = f2bf(d1 * rstd * g[lane + 64]  + b[lane + 64]);
    o[lane + 128] = f2bf(d2 * rstd * g[lane + 128] + b[lane + 128]);
}

// ---- bf16 MFMA GEMM, global_load_lds staging, 96-col K-slabs ----
// tile 128x64, 4 waves; LDS: A [128][104] shorts + B [64][104] shorts = 39936B.
// Per 96-col slab: rows are 12 valid 16B chunks + 1 pad chunk (clamped source).
// Stride 208B = 52 dwords = 20 mod 32 -> 2-way bank (free) on frag reads.
// MODE 0: out bf16 = acc + bias, cols<192 scaled by QSC (qkv: pre-scale Q)
// MODE 1: out f32  = acc + bias + res            (proj + shortcut)
// MODE 2: out bf16 = gelu(acc + bias)            (fc1)
// MODE 3: out f32  = acc + bias + out (in-place) (fc2 + x2)
template <int MODE, int KK>
__global__ __launch_bounds__(256, 4) void gemm_kernel(
    const unsigned short* __restrict__ A,
    const unsigned short* __restrict__ Wt,
    const float* __restrict__ bias,
    const float* __restrict__ res,
    void* __restrict__ outp,
    int N) {
    __shared__ __align__(16) short sAB[19968];   // A: 13312 shorts, B at 13312
    constexpr int STAGES = KK / 96;
    int tid = threadIdx.x;
    int w = tid >> 6, lane = tid & 63;
    int bm = blockIdx.x, bn = blockIdx.y;
    int lr = lane & 15, h = lane >> 4;
    floatx4 acc[2][4];
    #pragma unroll
    for (int i = 0; i < 2; i++)
        #pragma unroll
        for (int j = 0; j < 4; j++) acc[i][j] = (floatx4){0.f, 0.f, 0.f, 0.f};

    unsigned ldsbase = (unsigned)(uintptr_t)&sAB[0];

    for (int s = 0; s < STAGES; s++) {
        if (s) __syncthreads();
        for (int W = w; W < 39; W += 4) {
            int o = W * 1024 + lane * 16;
            const unsigned short* src;
            if (o < 26624) {                       // A region (wave-uniform branch)
                int r = o / 208;
                int c = (o - r * 208) >> 4; c = c < 12 ? c : 11;
                src = &A[(size_t)(bm * 128 + r) * KK + s * 96 + c * 8];
            } else {
                int o2 = o - 26624;
                int r = o2 / 208;
                int c = (o2 - r * 208) >> 4; c = c < 12 ? c : 11;
                src = &Wt[(size_t)(bn * 64 + r) * KK + s * 96 + c * 8];
            }
            gload16(src, ldsbase + (unsigned)(W * 1024));
        }
        __syncthreads();
        #pragma unroll
        for (int kk = 0; kk < 3; kk++) {
            int kc = (kk * 4 + h) * 8;
            short8 a0 = *(const short8*)&sAB[(w * 32 + lr) * 104 + kc];
            short8 a1 = *(const short8*)&sAB[(w * 32 + 16 + lr) * 104 + kc];
            short8 b0 = *(const short8*)&sAB[13312 + (lr) * 104 + kc];
            short8 b1 = *(const short8*)&sAB[13312 + (16 + lr) * 104 + kc];
            short8 b2 = *(const short8*)&sAB[13312 + (32 + lr) * 104 + kc];
            short8 b3 = *(const short8*)&sAB[13312 + (48 + lr) * 104 + kc];
            acc[0][0] = mfma16(a0, b0, acc[0][0]);
            acc[0][1] = mfma16(a0, b1, acc[0][1]);
            acc[0][2] = mfma16(a0, b2, acc[0][2]);
            acc[0][3] = mfma16(a0, b3, acc[0][3]);
            acc[1][0] = mfma16(a1, b0, acc[1][0]);
            acc[1][1] = mfma16(a1, b1, acc[1][1]);
            acc[1][2] = mfma16(a1, b2, acc[1][2]);
            acc[1][3] = mfma16(a1, b3, acc[1][3]);
        }
    }

    int rowbase = bm * 128 + w * 32 + h * 4;
    int colbase = bn * 64;
    #pragma unroll
    for (int mi = 0; mi < 2; mi++) {
        #pragma unroll
        for (int ni = 0; ni < 4; ni++) {
            int c = colbase + ni * 16 + lr;
            float bv = bias[c];
            #pragma unroll
            for (int j = 0; j < 4; j++) {
                int r = rowbase + mi * 16 + j;
                size_t idx = (size_t)r * N + c;
                float v = acc[mi][ni][j] + bv;
                if (MODE == 0) {
                    if (c < 192) v *= QSC;
                    ((unsigned short*)outp)[idx] = f2bf(v);
                } else if (MODE == 1) {
                    ((float*)outp)[idx] = v + res[idx];
                } else if (MODE == 2) {
                    float gl = 0.5f * v * (1.f + erff(v * 0.70710678118654752f));
                    ((unsigned short*)outp)[idx] = f2bf(gl);
                } else {
                    ((float*)outp)[idx] = v + ((float*)outp)[idx];
                }
            }
        }
    }
}

// ---- MFMA windowed attention, two-phase pipelined edition ----
// Block = (window, head), 4 waves; wave w owns q-tiles i = w*4..w*4+3.
// Phase A (per chunk): all 4 QK tiles + exp + packed b64 P-writes into
// per-(wave,i) 2KB sPt regions. Phase B: tr-read P fragments with counted
// lgkmcnt(4) pipeline (never a mid-loop drain), PV MFMAs.
__global__ __launch_bounds__(256, 3) void attn_mfma_kernel(
    const unsigned short* __restrict__ qkv,
    const float* __restrict__ btf,
    unsigned short* __restrict__ out) {
    __shared__ __align__(16) short sK[2][2304];
    __shared__ __align__(16) short sV[2][2048];
    __shared__ __align__(16) short sPt[4][4096];
    int win = blockIdx.x, head = blockIdx.y;
    int iy = win / 12, ix = win % 12;
    int tid = threadIdx.x;
    int w = tid >> 6, lane = tid & 63;
    int m = lane & 15, h = lane >> 4;

    // Q fragments (pre-scaled by SCALE*log2e in the qkv GEMM epilogue)
    short8 qf[4];
    #pragma unroll
    for (int i = 0; i < 4; i++) {
        int wy = w * 4 + i;
        size_t tok = (size_t)(iy * 16 + wy) * HW + ix * 16 + m;
        qf[i] = *(const short8*)&qkv[tok * 576 + head * 32 + h * 8];
    }

    short ob = (m == 0) ? (short)0x3F80 : (short)0;
    short8 bones = {ob, ob, ob, ob, ob, ob, ob, ob};

    floatx4 oacc[4][2];
    floatx4 lacc[4];
    #pragma unroll
    for (int i = 0; i < 4; i++) {
        lacc[i] = (floatx4){0.f, 0.f, 0.f, 0.f};
        oacc[i][0] = (floatx4){0.f, 0.f, 0.f, 0.f};
        oacc[i][1] = (floatx4){0.f, 0.f, 0.f, 0.f};
    }

    int skey = tid >> 2, dq = tid & 3;
    short* kdst = &sK[0][skey * 36 + dq * 8];
    short* vdst = &sV[0][(dq >> 1) * 1024 + (skey >> 2) * 64 + (skey & 3) * 16 + (dq & 1) * 8];

    auto fetch = [&](int c, short8& kv, short8& vv) {
        int key = c * 64 + skey;
        int oy = key / 24, ox = key - (key / 24) * 24;
        int gy = iy * 16 - 4 + oy, gx = ix * 16 - 4 + ox;
        kv = (short8){0,0,0,0,0,0,0,0};
        vv = (short8){0,0,0,0,0,0,0,0};
        if (gy >= 0 && gy < HW && gx >= 0 && gx < HW) {
            const unsigned short* p = &qkv[((size_t)gy * HW + gx) * 576 + 192 + head * 32 + dq * 8];
            kv = *(const short8*)p;
            vv = *(const short8*)(p + 192);
        }
    };

    {   // stage chunk 0 into buffer 0
        short8 kv, vv;
        fetch(0, kv, vv);
        *(short8*)kdst = kv;
        *(short8*)vdst = vv;
    }

    unsigned sPbase = (unsigned)(uintptr_t)&sPt[w][0];
    unsigned sPa = sPbase + 8 * m + 256 * h;            // tr-read base (per i: +2048*i)
    unsigned sVa0 = (unsigned)(uintptr_t)&sV[0][0] + 8 * m + 256 * h;
    char* sPwb = (char*)&sPt[w][0] + 128 * (m >> 2) + 32 * (m & 3) + 8 * h;

    for (int c = 0; c < 9; c++) {
        __syncthreads();
        int cur = c & 1;
        short8 knx, vnx;
        bool more = (c < 8);
        if (more) fetch(c + 1, knx, vnx);   // loads in flight during compute

        const short* sKc = sK[cur];
        short8 kfrag[4];
        #pragma unroll
        for (int kt = 0; kt < 4; kt++)
            kfrag[kt] = *(const short8*)&sKc[(kt * 16 + m) * 36 + h * 8];

        const float* bb = btf + ((((size_t)head * 16 + w * 4) * 36 + c * 4) * 64 + lane) * 4;

        // ---- Phase A: QK + exp + P writes for all 4 q-tiles ----
        #pragma unroll
        for (int i = 0; i < 4; i++) {
            floatx4 s[4];
            #pragma unroll
            for (int kt = 0; kt < 4; kt++)
                s[kt] = *(const floatx4*)&bb[(size_t)(i * 36 + kt) * 256];
            #pragma unroll
            for (int kt = 0; kt < 4; kt++)
                s[kt] = mfma16(qf[i], kfrag[kt], s[kt]);
            #pragma unroll
            for (int kt = 0; kt < 4; kt++) {
                s16x4 pk;
                #pragma unroll
                for (int r = 0; r < 4; r++)
                    pk[r] = f2bfh(exp2fast(s[kt][r]));
                *(s16x4*)(sPwb + i * 2048 + kt * 512) = pk;
            }
        }

        // ---- Phase B: pipelined tr reads + PV ----
        unsigned sVa = sVa0 + cur * 4096;
        short8 vb[4];
        {
            s16x4 lo0 = tr16<0>(sVa),    hi0 = tr16<128>(sVa);
            s16x4 lo1 = tr16<2048>(sVa), hi1 = tr16<2176>(sVa);
            s16x4 lo2 = tr16<1024>(sVa), hi2 = tr16<1152>(sVa);
            s16x4 lo3 = tr16<3072>(sVa), hi3 = tr16<3200>(sVa);
            vb[0] = cat8(lo0, hi0);
            vb[1] = cat8(lo1, hi1);
            vb[2] = cat8(lo2, hi2);
            vb[3] = cat8(lo3, hi3);
        }
        s16x4 pl0 = tr16m<0>(sPa),    ph0 = tr16m<128>(sPa);
        s16x4 pl1 = tr16m<1024>(sPa), ph1 = tr16m<1152>(sPa);
        #pragma unroll
        for (int i = 0; i < 4; i++) {
            s16x4 nl0, nh0, nl1, nh1;
            if (i < 3) {
                unsigned a = sPa + (unsigned)((i + 1) * 2048);
                nl0 = tr16m<0>(a);    nh0 = tr16m<128>(a);
                nl1 = tr16m<1024>(a); nh1 = tr16m<1152>(a);
                wait_lgkm<4>();
            } else {
                wait_lgkm<0>();
            }
            __builtin_amdgcn_sched_barrier(0);
            short8 pa0 = cat8(pl0, ph0);
            short8 pa1 = cat8(pl1, ph1);
            oacc[i][0] = mfma16(pa0, vb[0], oacc[i][0]);
            oacc[i][1] = mfma16(pa0, vb[1], oacc[i][1]);
            oacc[i][0] = mfma16(pa1, vb[2], oacc[i][0]);
            oacc[i][1] = mfma16(pa1, vb[3], oacc[i][1]);
            lacc[i] = mfma16(pa0, bones, lacc[i]);
            lacc[i] = mfma16(pa1, bones, lacc[i]);
            if (i < 3) { pl0 = nl0; ph0 = nh0; pl1 = nl1; ph1 = nh1; }
        }

        if (more) {   // write prefetched chunk into the other buffer
            int nb = 1 - cur;
            *(short8*)(kdst + nb * 2304) = knx;
            *(short8*)(vdst + nb * 2048) = vnx;
        }
    }

    // ---- normalize + store ----
    #pragma unroll
    for (int i = 0; i < 4; i++) {
        float inv[4];
        #pragma unroll
        for (int r = 0; r < 4; r++) {
            float sum = __shfl(lacc[i][r], lane & 48);
            inv[r] = 1.f / sum;
        }
        int wy = w * 4 + i;
        #pragma unroll
        for (int dt = 0; dt < 2; dt++)
            #pragma unroll
            for (int r = 0; r < 4; r++) {
                size_t tok = (size_t)(iy * 16 + wy) * HW + ix * 16 + h * 4 + r;
                out[tok * DIM + head * 32 + dt * 16 + m] = f2bf(oacc[i][dt][r] * inv[r]);
            }
    }
}

extern "C" void kernel_launch(void* const* d_in, const int* in_sizes, int n_in,
                              void* d_out, int out_size, void* d_ws, size_t ws_size,
                              hipStream_t stream) {
    const float* x     = (const float*)d_in[0];
    const int*   rpi   = (const int*)d_in[1];
    const float* n1g   = (const float*)d_in[4];
    const float* n1b   = (const float*)d_in[5];
    const float* qkvw  = (const float*)d_in[6];
    const float* qkvb  = (const float*)d_in[7];
    const float* rpb   = (const float*)d_in[8];
    const float* projw = (const float*)d_in[9];
    const float* projb = (const float*)d_in[10];
    const float* n2g   = (const float*)d_in[11];
    const float* n2b   = (const float*)d_in[12];
    const float* fc1w  = (const float*)d_in[13];
    const float* fc1b  = (const float*)d_in[14];
    const float* fc2w  = (const float*)d_in[15];
    const float* fc2b  = (const float*)d_in[16];

    char* ws = (char*)d_ws;
    unsigned short* wt_qkv  = (unsigned short*)ws;          // 110592 elems
    unsigned short* wt_proj = wt_qkv + 110592;              // 36864
    unsigned short* wt_fc1  = wt_proj + 36864;              // 73728
    unsigned short* wt_fc2  = wt_fc1 + 73728;               // 73728
    float*          btf     = (float*)(ws + 589824);        // 884736 f32 (frag-order bias)
    unsigned short* xn      = (unsigned short*)(ws + 4128768);   // 36864*192 bf16
    unsigned short* qkv     = (unsigned short*)(ws + 18284544);  // 36864*576 bf16
    unsigned short* attn_o  = (unsigned short*)(ws + 60751872);  // 36864*192 bf16
    float* outf = (float*)d_out;

    wcast_kernel<<<(110592 + 255) / 256, 256, 0, stream>>>(qkvw, wt_qkv, 192, 576);
    wcast_kernel<<<(36864 + 255) / 256, 256, 0, stream>>>(projw, wt_proj, 192, 192);
    wcast_kernel<<<(73728 + 255) / 256, 256, 0, stream>>>(fc1w, wt_fc1, 192, 384);
    wcast_kernel<<<(73728 + 255) / 256, 256, 0, stream>>>(fc2w, wt_fc2, 384, 192);
    btfrag_kernel<<<(221184 + 255) / 256, 256, 0, stream>>>(rpi, rpb, btf);
    ln_kernel<<<M_TOK / 4, 256, 0, stream>>>(x, n1g, n1b, xn);
    gemm_kernel<0, 192><<<dim3(288, 9), 256, 0, stream>>>(
        xn, wt_qkv, qkvb, nullptr, qkv, 576);
    attn_mfma_kernel<<<dim3(144, 6), 256, 0, stream>>>(qkv, btf, attn_o);
    gemm_kernel<1, 192><<<dim3(288, 3), 256, 0, stream>>>(
        attn_o, wt_proj, projb, x, d_out, 192);
    ln_kernel<<<M_TOK / 4, 256, 0, stream>>>(outf, n2g, n2b, xn);
    gemm_kernel<2, 192><<<dim3(288, 6), 256, 0, stream>>>(
        xn, wt_fc1, fc1b, nullptr, qkv, 384);
    gemm_kernel<3, 384><<<dim3(288, 3), 256, 0, stream>>>(
        qkv, wt_fc2, fc2b, nullptr, d_out, 192);
}